// Round 2
// baseline (7291.418 us; speedup 1.0000x reference)
//
#include <hip/hip_runtime.h>
#include <stdint.h>

// ManifoldRNN: B=64, S=2048, I=H=O=256, L=2.
//   1) prep: swizzle w_h0, w_q -> fp16 MFMA-B-fragment layout (ws)
//   2) gemm256<fp32->fp16>: A0 = x@w_h0 + b_h0  -> d_out[0:67MB) as fp16
//   3) rnn_pipe: 192 blocks = 3 pipeline stages x 64 batches, 4 waves each
//      (1 wave/SIMD, __launch_bounds__(256,1) so w[128] stays in VGPRs —
//       round-1's VGPR_Count=84 proved the weights spilled to scratch).
//      Cross-block handoff: fp16 rings in d_out dead space + device-scope
//      monotone progress counters (release/acquire, AGENT scope).
//   4) gemm256<fp16->fp32>: y = H1@w_q + b_q -> d_out
#define S_LEN 2048
#define NB    64
#define HD    256
#define RING  1024
#define RMASK 1023

typedef _Float16 half2_t  __attribute__((ext_vector_type(2)));
typedef _Float16 half8_t  __attribute__((ext_vector_type(8)));
typedef float    floatx4  __attribute__((ext_vector_type(4)));
typedef float    floatx8  __attribute__((ext_vector_type(8)));
typedef float    floatx16 __attribute__((ext_vector_type(16)));

__device__ __forceinline__ float fdot2(half2_t a, half2_t b, float c){
#if __has_builtin(__builtin_amdgcn_fdot2)
  return __builtin_amdgcn_fdot2(a, b, c, false);
#else
  return c + (float)a[0]*(float)b[0] + (float)a[1]*(float)b[1];
#endif
}

__device__ __forceinline__ float tanh_fast(float x){
  float e = __expf(2.0f * x);
  return 1.0f - 2.0f / (e + 1.0f);
}

// Full-K(256) fp16 dot of broadcast h (LDS or global, all lanes same addr)
// against a 128-VGPR register-resident column. 4 accumulators for ILP.
#define MATVEC(HS, WREG, ACC)                                                     \
  {                                                                               \
    float a0_=0.f, a1_=0.f, a2_=0.f, a3_=0.f;                                     \
    _Pragma("unroll")                                                             \
    for (int i_ = 0; i_ < 32; ++i_){                                              \
      half8_t c_ = (HS)[i_];                                                      \
      a0_ = fdot2(__builtin_shufflevector(c_, c_, 0, 1), (WREG)[4*i_+0], a0_);    \
      a1_ = fdot2(__builtin_shufflevector(c_, c_, 2, 3), (WREG)[4*i_+1], a1_);    \
      a2_ = fdot2(__builtin_shufflevector(c_, c_, 4, 5), (WREG)[4*i_+2], a2_);    \
      a3_ = fdot2(__builtin_shufflevector(c_, c_, 6, 7), (WREG)[4*i_+3], a3_);    \
    }                                                                             \
    ACC = (a0_ + a1_) + (a2_ + a3_);                                              \
  }

// ---------------------------------------------------------------------------
// 3-stage pipelined recurrence. blockIdx = stage*64 + b (stage-major so the
// three blocks of one batch share an XCD residue class for L2 locality).
//   stage 0: h0(t) = tanh(A0(t) + h0(t-1)@u_h0)        -> h0ring, prog0
//   stage 1: wp(t) = h0(t)@w_h1                         -> wpring, prog2
//   stage 2: h1(t) = tanh(wp(t) + h1(t-1)@u_h1 + b_h1)  -> H1, prog1 (coarse)
// ---------------------------------------------------------------------------
__launch_bounds__(256, 1)
__global__ void rnn_pipe(const _Float16* __restrict__ A0,
                         const float* __restrict__ u_h0,
                         const float* __restrict__ w_h1,
                         const float* __restrict__ u_h1,
                         const float* __restrict__ b_h1,
                         _Float16* __restrict__ H1,
                         float* __restrict__ hfinal,
                         _Float16* __restrict__ h0ring,
                         _Float16* __restrict__ wpring,
                         uint32_t* __restrict__ flags)
{
  const int stage = blockIdx.x >> 6;
  const int b     = blockIdx.x & 63;
  const int col   = threadIdx.x;          // 256 threads = 4 waves

  __shared__ __align__(16) _Float16 hbuf[2][HD];
  hbuf[0][col] = (_Float16)0.f;
  hbuf[1][col] = (_Float16)0.f;

  uint32_t* prog0 = flags +        (b << 4);
  uint32_t* prog2 = flags + 1024 + (b << 4);
  uint32_t* prog1 = flags + 2048 + (b << 4);

  // Register-resident fp16 weight column (128 VGPRs; budget is ~512 at 1 wave/SIMD).
  const float* Wm = (stage == 0) ? u_h0 : (stage == 1) ? w_h1 : u_h1;
  half2_t w[128];
  #pragma unroll
  for (int i = 0; i < 128; ++i){
    float w0 = Wm[(2*i)     * HD + col];
    float w1 = Wm[(2*i + 1) * HD + col];
    half2_t p; p[0] = (_Float16)w0; p[1] = (_Float16)w1;
    w[i] = p;
  }

  const size_t base = (size_t)b * S_LEN * HD;
  int budget = 1 << 24;                   // hang-safety valve: break => wrong, not hung

  __syncthreads();

  if (stage == 0){
    uint32_t c2 = 0;
    _Float16 a0n1 = A0[base + col];
    _Float16 a0n2 = A0[base + HD + col];
    for (int t = 0; t < S_LEN; ++t){
      _Float16 a0c = a0n1; a0n1 = a0n2;
      if (t + 2 < S_LEN) a0n2 = A0[base + (size_t)(t + 2) * HD + col]; // issue early
      if (t >= RING){                      // backpressure (RING slack: ~never spins)
        uint32_t want = (uint32_t)(t - RING + 1);
        while (c2 < want && budget-- > 0)
          c2 = __hip_atomic_load(prog2, __ATOMIC_ACQUIRE, __HIP_MEMORY_SCOPE_AGENT);
      }
      const half8_t* hs = (const half8_t*)&hbuf[(t + 1) & 1][0];
      float acc; MATVEC(hs, w, acc);
      float h = tanh_fast(acc + (float)a0c);
      hbuf[t & 1][col] = (_Float16)h;
      h0ring[(size_t)((b << 10) | (t & RMASK)) * HD + col] = (_Float16)h;
      if (t == S_LEN - 1) hfinal[(b << 9) + col] = h;
      __syncthreads();                     // drains vmem (h0ring stores) before publish
      if (col == 0)
        __hip_atomic_store(prog0, (uint32_t)(t + 1), __ATOMIC_RELEASE, __HIP_MEMORY_SCOPE_AGENT);
    }
  } else if (stage == 1){
    uint32_t c0 = 0, c1 = 0;
    for (int t = 0; t < S_LEN; ++t){
      if (t >= RING){
        uint32_t want = (uint32_t)(t - RING + 1);
        while (c1 < want && budget-- > 0)
          c1 = __hip_atomic_load(prog1, __ATOMIC_ACQUIRE, __HIP_MEMORY_SCOPE_AGENT);
      }
      uint32_t want = (uint32_t)(t + 1);
      while (c0 < want && budget-- > 0)
        c0 = __hip_atomic_load(prog0, __ATOMIC_ACQUIRE, __HIP_MEMORY_SCOPE_AGENT);
      const half8_t* hs = (const half8_t*)(h0ring + (size_t)((b << 10) | (t & RMASK)) * HD);
      float acc; MATVEC(hs, w, acc);
      wpring[(size_t)((b << 10) | (t & RMASK)) * HD + col] = (_Float16)acc;
      __syncthreads();
      if (col == 0)
        __hip_atomic_store(prog2, (uint32_t)(t + 1), __ATOMIC_RELEASE, __HIP_MEMORY_SCOPE_AGENT);
    }
  } else {
    const float bias = b_h1[col];
    uint32_t c2 = 0;
    for (int t = 0; t < S_LEN; ++t){
      uint32_t want = (uint32_t)(t + 1);
      while (c2 < want && budget-- > 0)
        c2 = __hip_atomic_load(prog2, __ATOMIC_ACQUIRE, __HIP_MEMORY_SCOPE_AGENT);
      float wp = (float)wpring[(size_t)((b << 10) | (t & RMASK)) * HD + col];
      const half8_t* hs = (const half8_t*)&hbuf[(t + 1) & 1][0];
      float acc; MATVEC(hs, w, acc);
      float h = tanh_fast(acc + wp + bias);
      hbuf[t & 1][col] = (_Float16)h;
      H1[base + (size_t)t * HD + col] = (_Float16)h;
      if (t == S_LEN - 1) hfinal[(b << 9) + HD + col] = h;
      __syncthreads();
      if (col == 0 && (((t & 15) == 15) || t == S_LEN - 1))   // coarse: only for backpressure
        __hip_atomic_store(prog1, (uint32_t)(t + 1), __ATOMIC_RELEASE, __HIP_MEMORY_SCOPE_AGENT);
    }
  }
}

// ---------------------------------------------------------------------------
// Swizzle B (fp32 [256,256]) -> fp16 MFMA-B-frag layout: (k>>3)*2048 + n*8 + (k&7)
// ---------------------------------------------------------------------------
__global__ void prep_kernel(const float* __restrict__ w0, const float* __restrict__ wq,
                            _Float16* __restrict__ B0, _Float16* __restrict__ Bq)
{
  int i = blockIdx.x * 256 + threadIdx.x;
  for (int idx = i; idx < 65536; idx += 64 * 256){
    int k = idx >> 8, n = idx & 255;
    int sw = (k >> 3) * 2048 + n * 8 + (k & 7);
    B0[sw] = (_Float16)w0[idx];
    Bq[sw] = (_Float16)wq[idx];
  }
}

// ---------------------------------------------------------------------------
// C[131072,256] = A[131072,256] @ B[256,256] + bias via fp16 mfma 32x32x16.
// ---------------------------------------------------------------------------
template<bool A_FP32, bool C_FP16>
__launch_bounds__(512)
__global__ void gemm256(const void* __restrict__ Ap,
                        const _Float16* __restrict__ Bsw,
                        const float* __restrict__ bias,
                        void* __restrict__ Cp)
{
  const int wave = threadIdx.x >> 6;
  const int lane = threadIdx.x & 63;
  const int r  = lane & 31;
  const int hf = lane >> 5;
  const size_t rowt = (size_t)blockIdx.x * 256 + (size_t)wave * 32;

  floatx16 acc[8];
  #pragma unroll
  for (int i = 0; i < 8; ++i)
    #pragma unroll
    for (int j = 0; j < 16; ++j) acc[i][j] = 0.f;

  const size_t arow = rowt + (size_t)r;
  #pragma unroll
  for (int ks = 0; ks < 16; ++ks){
    half8_t af;
    if (A_FP32){
      const float* A = (const float*)Ap;
      const floatx4* p = (const floatx4*)(A + arow * 256 + ks * 16 + hf * 8);
      floatx4 v0 = p[0], v1 = p[1];
      floatx8 v = __builtin_shufflevector(v0, v1, 0, 1, 2, 3, 4, 5, 6, 7);
      af = __builtin_convertvector(v, half8_t);
    } else {
      const _Float16* A = (const _Float16*)Ap;
      af = *(const half8_t*)(A + arow * 256 + ks * 16 + hf * 8);
    }
    #pragma unroll
    for (int ct = 0; ct < 8; ++ct){
      half8_t bf = *(const half8_t*)(Bsw + (size_t)(ks * 2 + hf) * 2048 + (ct * 32 + r) * 8);
      acc[ct] = __builtin_amdgcn_mfma_f32_32x32x16_f16(af, bf, acc[ct], 0, 0, 0);
    }
  }

  #pragma unroll
  for (int ct = 0; ct < 8; ++ct){
    const int col = ct * 32 + r;
    const float bc = bias[col];
    #pragma unroll
    for (int reg = 0; reg < 16; ++reg){
      const int rl = (reg & 3) + 8 * (reg >> 2) + 4 * hf;
      const size_t idx = (rowt + rl) * 256 + col;
      float v = acc[ct][reg] + bc;
      if (C_FP16) ((_Float16*)Cp)[idx] = (_Float16)v;
      else        ((float*)Cp)[idx]    = v;
    }
  }
}

extern "C" void kernel_launch(void* const* d_in, const int* in_sizes, int n_in,
                              void* d_out, int out_size, void* d_ws, size_t ws_size,
                              hipStream_t stream)
{
  (void)in_sizes; (void)n_in; (void)out_size; (void)ws_size;

  const float* x    = (const float*)d_in[0];
  const float* w_h0 = (const float*)d_in[1];
  const float* u_h0 = (const float*)d_in[2];
  const float* b_h0 = (const float*)d_in[3];
  const float* w_h1 = (const float*)d_in[4];
  const float* u_h1 = (const float*)d_in[5];
  const float* b_h1 = (const float*)d_in[6];
  const float* w_q  = (const float*)d_in[7];
  const float* b_q  = (const float*)d_in[8];

  const size_t MSH = (size_t)NB * S_LEN * HD;   // 33,554,432

  // d_out dead-space plan (all consumed before the final y-GEMM writes):
  //   fp16[0,     MSH)        : A0
  //   fp16[MSH,   MSH+MSH/2)  : h0ring (64 x 1024 x 256)
  //   fp16[MSH+MSH/2, 2*MSH)  : wpring  — ends exactly at y's end
  //   float[MSH ...]          : hfinal (beyond y, untouched by rings)
  float*    y      = (float*)d_out;
  float*    hfin   = y + MSH;
  _Float16* A0     = (_Float16*)d_out;
  _Float16* h0ring = A0 + MSH;
  _Float16* wpring = h0ring + MSH / 2;

  // ws: H1 (67MB) + swizzled B (512KB) + flags (12KB)
  _Float16* H1    = (_Float16*)d_ws;
  _Float16* B0sw  = H1 + MSH;
  _Float16* Bqsw  = B0sw + 65536;
  uint32_t* flags = (uint32_t*)(Bqsw + 65536);

  hipMemsetAsync((void*)flags, 0, 3072 * sizeof(uint32_t), stream);
  prep_kernel<<<dim3(64), dim3(256), 0, stream>>>(w_h0, w_q, B0sw, Bqsw);
  gemm256<true, true><<<dim3(512), dim3(512), 0, stream>>>((const void*)x, B0sw, b_h0, (void*)A0);
  rnn_pipe<<<dim3(192), dim3(256), 0, stream>>>(A0, u_h0, w_h1, u_h1, b_h1,
                                                H1, hfin, h0ring, wpring, flags);
  gemm256<false, false><<<dim3(512), dim3(512), 0, stream>>>((const void*)H1, Bqsw, b_q, (void*)y);
}